// Round 6
// baseline (101.982 us; speedup 1.0000x reference)
//
#include <hip/hip_runtime.h>

// FeatureEmbedder: out[b, f*64+d] = relu(x[b,f] * W[f,d] + b[f,d])
// x: [16384, 128] f32, W: [128, 64] f32, b: [128, 64] f32
// out: [16384, 8192] f32  (512 MB -> HBM-write-bound)
//
// R6: per-WAVE linear store runs. R5 fixed each thread's column, so a wave's
// consecutive stores were 1 KB runs with a 4 KB stride (holes filled by the
// block's other, drifting waves). Here wave w owns the contiguous 8 KB slice
// [w*512, w*512+512) float4 of each row (col4 = w*512 + j*64 + lane, j inner)
// -> each wave writes 8 consecutive 1 KB stores per row; the 4 waves tile the
// 32 KB row exactly and rows ascend, so the block's 1 MB region is swept
// linearly at every granularity. Same W/b hoisting (8 pairs, j-indexed),
// same 16 KB x LDS tile, same occupancy as R5.

#define BATCH 16384
#define NFEAT 128
#define EMBD  64
#define ROW4  (NFEAT * EMBD / 4)   // 2048 float4 per output row

typedef float vfloat4 __attribute__((ext_vector_type(4)));

__global__ __launch_bounds__(256) void feature_embed_kernel(
    const vfloat4* __restrict__ x4,
    const vfloat4* __restrict__ W4,
    const vfloat4* __restrict__ B4,
    vfloat4* __restrict__ out4) {

    __shared__ float xs[32 * NFEAT];      // 16 KB: x rows 32b .. 32b+31

    const int tid  = threadIdx.x;         // 0..255
    const int b    = blockIdx.x;          // 0..511
    const int w    = tid >> 6;            // wave id, 0..3
    const int lane = tid & 63;

    // Thread's column for sub-chunk j: col4 = w*512 + j*64 + lane, j = 0..7.
    const int cb = w * 512 + lane;
    vfloat4 wv[8], bv[8];
    #pragma unroll
    for (int j = 0; j < 8; ++j) {
        wv[j] = W4[cb + j * 64];
        bv[j] = B4[cb + j * 64];
    }

    // Stage x rows 32b..32b+31 (4096 floats = 1024 float4, contiguous in x).
    #pragma unroll
    for (int k = 0; k < 4; ++k)
        ((vfloat4*)xs)[k * 256 + tid] = x4[b * 1024 + k * 256 + tid];
    __syncthreads();

    const int fs = lane >> 4;             // 0..3: feature sub-index in chunk
    const int fb = w * 32 + fs;           // + j*4 gives this thread's feature
    vfloat4* outb = out4 + b * 32 * ROW4; // this block's 1 MB region

    #pragma unroll 4
    for (int r = 0; r < 32; ++r) {
        const float* xr = xs + r * NFEAT;
        vfloat4* outr = outb + r * ROW4 + cb;
        #pragma unroll
        for (int j = 0; j < 8; ++j) {
            const float xv = xr[fb + j * 4];      // ds_read broadcast
            vfloat4 o;
            o.x = fmaxf(fmaf(xv, wv[j].x, bv[j].x), 0.0f);
            o.y = fmaxf(fmaf(xv, wv[j].y, bv[j].y), 0.0f);
            o.z = fmaxf(fmaf(xv, wv[j].z, bv[j].z), 0.0f);
            o.w = fmaxf(fmaf(xv, wv[j].w, bv[j].w), 0.0f);
            // Wave-linear: j-th consecutive 1 KB store of this row's slice.
            outr[j * 64] = o;
        }
    }
}

extern "C" void kernel_launch(void* const* d_in, const int* in_sizes, int n_in,
                              void* d_out, int out_size, void* d_ws, size_t ws_size,
                              hipStream_t stream) {
    const vfloat4* x4 = (const vfloat4*)d_in[0];
    const vfloat4* W4 = (const vfloat4*)d_in[1];
    const vfloat4* B4 = (const vfloat4*)d_in[2];
    vfloat4* out4     = (vfloat4*)d_out;

    // 512 blocks x 256 threads; block b writes rows [32b, 32b+32) linearly.
    feature_embed_kernel<<<512, 256, 0, stream>>>(x4, W4, B4, out4);
}